// Round 3
// baseline (334.634 us; speedup 1.0000x reference)
//
#include <hip/hip_runtime.h>

#define DIMB 2
#define DIMS 192
#define DPT 4        // d-outputs per thread
#define TX 16        // d-quads per block (64 d per block)
#define TY 16        // w rows per block
#define HCHUNK 6     // h rows per block

// Raw 6-float d-windows (d0-1 .. d0+4) for 3 w-columns, both arrays.
struct Raw { float p[3][6]; float t[3][6]; };

__device__ __forceinline__ void load_raw(
    const float* __restrict__ pred, const float* __restrict__ targ,
    int b, int hh, int w, int d0, Raw& r)
{
    const bool hok = (hh >= 0) & (hh < DIMS);
#pragma unroll
    for (int dw = 0; dw < 3; ++dw) {
        const int wc = w - 1 + dw;
        if (hok && wc >= 0 && wc < DIMS) {
            const int base = ((b * DIMS + hh) * DIMS + wc) * DIMS + d0;
            const float4 p4 = *reinterpret_cast<const float4*>(pred + base);
            const float4 t4 = *reinterpret_cast<const float4*>(targ + base);
            r.p[dw][1] = p4.x; r.p[dw][2] = p4.y; r.p[dw][3] = p4.z; r.p[dw][4] = p4.w;
            r.t[dw][1] = t4.x; r.t[dw][2] = t4.y; r.t[dw][3] = t4.z; r.t[dw][4] = t4.w;
            r.p[dw][0] = (d0 > 0)          ? pred[base - 1] : 0.f;
            r.t[dw][0] = (d0 > 0)          ? targ[base - 1] : 0.f;
            r.p[dw][5] = (d0 + DPT < DIMS) ? pred[base + DPT] : 0.f;
            r.t[dw][5] = (d0 + DPT < DIMS) ? targ[base + DPT] : 0.f;
        } else {
#pragma unroll
            for (int k = 0; k < 6; ++k) { r.p[dw][k] = 0.f; r.t[dw][k] = 0.f; }
        }
    }
}

// 3x3 (w,d)-plane sums of the 5 product channels from raw values.
__device__ __forceinline__ void plane_sums(const Raw& r, float (&P)[5][DPT])
{
#pragma unroll
    for (int c = 0; c < 5; ++c)
#pragma unroll
        for (int j = 0; j < DPT; ++j) P[c][j] = 0.f;
#pragma unroll
    for (int dw = 0; dw < 3; ++dw) {
        float pp[6], tt[6], pt[6];
#pragma unroll
        for (int k = 0; k < 6; ++k) {
            pp[k] = r.p[dw][k] * r.p[dw][k];
            tt[k] = r.t[dw][k] * r.t[dw][k];
            pt[k] = r.p[dw][k] * r.t[dw][k];
        }
#pragma unroll
        for (int j = 0; j < DPT; ++j) {
            P[0][j] += r.p[dw][j] + r.p[dw][j+1] + r.p[dw][j+2];
            P[1][j] += r.t[dw][j] + r.t[dw][j+1] + r.t[dw][j+2];
            P[2][j] += pp[j] + pp[j+1] + pp[j+2];
            P[3][j] += tt[j] + tt[j+1] + tt[j+2];
            P[4][j] += pt[j] + pt[j+1] + pt[j+2];
        }
    }
}

// Emit ncc for one output row given S2 = P(h-1)+P(h) and Pn = P(h+1).
__device__ __forceinline__ float ncc_row(const float (&S2)[5][DPT],
                                         const float (&Pn)[5][DPT])
{
    const float inv = 1.0f / 27.0f;
    float acc = 0.f;
#pragma unroll
    for (int j = 0; j < DPT; ++j) {
        const float sI  = S2[0][j] + Pn[0][j];
        const float sJ  = S2[1][j] + Pn[1][j];
        const float sII = S2[2][j] + Pn[2][j];
        const float sJJ = S2[3][j] + Pn[3][j];
        const float sIJ = S2[4][j] + Pn[4][j];
        const float uI = sI * inv;
        const float uJ = sJ * inv;
        const float cross = sIJ - uI * sJ;
        const float pvar  = sII - uI * sI;
        const float tvar  = sJJ - uJ * sJ;
        acc += (cross * cross) * __builtin_amdgcn_rcpf(tvar * pvar + 1e-5f);
    }
    return acc;
}

__global__ __launch_bounds__(256, 3)
void FusedLocalNormalizedCrossCorrelationLoss_37838661877790_kernel(
    const float* __restrict__ pred, const float* __restrict__ targ,
    double* __restrict__ acc_out)
{
    const int tx = threadIdx.x;                 // 16 d-quads
    const int ty = threadIdx.y;                 // 16 w rows
    const int d0 = (blockIdx.x * TX + tx) * DPT;
    const int w  = blockIdx.y * TY + ty;
    const int bz = blockIdx.z;
    const int b  = bz >> 5;                     // 2 batches
    const int h0 = (bz & 31) * HCHUNK;          // 32 h-chunks

    // Prologue: planes h0-1 and h0 -> S2, Pc; issue loads for plane h0+1.
    Raw rA, rB, rbuf[2];
    load_raw(pred, targ, b, h0 - 1, w, d0, rA);
    load_raw(pred, targ, b, h0,     w, d0, rB);
    load_raw(pred, targ, b, h0 + 1, w, d0, rbuf[0]);

    float S2[5][DPT], Pc[5][DPT], Pn[5][DPT];
    plane_sums(rA, S2);      // temporarily P(h0-1)
    plane_sums(rB, Pc);
#pragma unroll
    for (int c = 0; c < 5; ++c)
#pragma unroll
        for (int j = 0; j < DPT; ++j) S2[c][j] += Pc[c][j];

    float acc = 0.f;
    // Pipelined rows h0 .. h0+HCHUNK-2: prefetch plane h+2 while consuming h+1.
#pragma unroll
    for (int i = 0; i < HCHUNK - 1; ++i) {
        load_raw(pred, targ, b, h0 + 2 + i, w, d0, rbuf[(i + 1) & 1]);
        plane_sums(rbuf[i & 1], Pn);
        acc += ncc_row(S2, Pn);
#pragma unroll
        for (int c = 0; c < 5; ++c)
#pragma unroll
            for (int j = 0; j < DPT; ++j) {
                S2[c][j] = Pc[c][j] + Pn[c][j];
                Pc[c][j] = Pn[c][j];
            }
    }
    // Peeled last row: no prefetch.
    plane_sums(rbuf[(HCHUNK - 1) & 1], Pn);
    acc += ncc_row(S2, Pn);

    // Reduction: wave shuffle tree -> LDS -> one fp64 atomic per block.
#pragma unroll
    for (int off = 32; off > 0; off >>= 1)
        acc += __shfl_down(acc, off, 64);
    __shared__ float wacc[4];
    const int tid = ty * TX + tx;
    if ((tid & 63) == 0) wacc[tid >> 6] = acc;
    __syncthreads();
    if (tid == 0) {
        const double s = (double)wacc[0] + (double)wacc[1]
                       + (double)wacc[2] + (double)wacc[3];
        atomicAdd(acc_out, s);
    }
}

__global__ void ncc_finalize(const double* __restrict__ acc,
                             float* __restrict__ out)
{
    const double n = (double)((size_t)DIMB * DIMS * DIMS * DIMS);
    out[0] = (float)(-acc[0] / n);
}

extern "C" void kernel_launch(void* const* d_in, const int* in_sizes, int n_in,
                              void* d_out, int out_size, void* d_ws, size_t ws_size,
                              hipStream_t stream) {
    const float* pred = (const float*)d_in[0];
    const float* targ = (const float*)d_in[1];
    double* acc = (double*)d_ws;

    hipMemsetAsync(d_ws, 0, sizeof(double), stream);

    dim3 block(TX, TY, 1);
    dim3 grid(DIMS / (TX * DPT), DIMS / TY, DIMB * (DIMS / HCHUNK)); // 3 x 12 x 64
    FusedLocalNormalizedCrossCorrelationLoss_37838661877790_kernel
        <<<grid, block, 0, stream>>>(pred, targ, acc);
    ncc_finalize<<<1, 1, 0, stream>>>(acc, (float*)d_out);
}

// Round 4
// 216.310 us; speedup vs baseline: 1.5470x; 1.5470x over previous
//
#include <hip/hip_runtime.h>

#define DIMB 2
#define DIMS 192
#define DPT 4        // d-outputs per thread
#define TX 16        // d-quads per block (64 d per block)
#define TY 16        // w rows per block
#define HCHUNK 6     // h rows per block

// Raw 6-float d-windows (d0-1 .. d0+4) for 3 w-columns, both arrays.
// NOTE: only ever indexed by compile-time constants (full unroll) so it
// lives in VGPRs — R3's rotating rbuf[i&1] was demoted to scratch (443 MB
// of spill traffic); named buffers + manual unroll make that impossible.
struct Raw { float p[3][6]; float t[3][6]; };

__device__ __forceinline__ void load_raw(
    const float* __restrict__ pred, const float* __restrict__ targ,
    int b, int hh, int w, int d0, Raw& r)
{
    const bool hok = (hh >= 0) & (hh < DIMS);
#pragma unroll
    for (int dw = 0; dw < 3; ++dw) {
        const int wc = w - 1 + dw;
        if (hok && wc >= 0 && wc < DIMS) {
            const int base = ((b * DIMS + hh) * DIMS + wc) * DIMS + d0;
            const float4 p4 = *reinterpret_cast<const float4*>(pred + base);
            const float4 t4 = *reinterpret_cast<const float4*>(targ + base);
            r.p[dw][1] = p4.x; r.p[dw][2] = p4.y; r.p[dw][3] = p4.z; r.p[dw][4] = p4.w;
            r.t[dw][1] = t4.x; r.t[dw][2] = t4.y; r.t[dw][3] = t4.z; r.t[dw][4] = t4.w;
            r.p[dw][0] = (d0 > 0)          ? pred[base - 1] : 0.f;
            r.t[dw][0] = (d0 > 0)          ? targ[base - 1] : 0.f;
            r.p[dw][5] = (d0 + DPT < DIMS) ? pred[base + DPT] : 0.f;
            r.t[dw][5] = (d0 + DPT < DIMS) ? targ[base + DPT] : 0.f;
        } else {
#pragma unroll
            for (int k = 0; k < 6; ++k) { r.p[dw][k] = 0.f; r.t[dw][k] = 0.f; }
        }
    }
}

// 3x3 (w,d)-plane sums of the 5 product channels from raw values.
__device__ __forceinline__ void plane_sums(const Raw& r, float (&P)[5][DPT])
{
    // Fold w first (fewer window adds), products per column on the fly.
    float W0[6], W1[6], W2[6], W3[6], W4[6];
#pragma unroll
    for (int k = 0; k < 6; ++k) {
        const float p0 = r.p[0][k], p1 = r.p[1][k], p2 = r.p[2][k];
        const float t0 = r.t[0][k], t1 = r.t[1][k], t2 = r.t[2][k];
        W0[k] = p0 + p1 + p2;
        W1[k] = t0 + t1 + t2;
        W2[k] = p0*p0 + p1*p1 + p2*p2;
        W3[k] = t0*t0 + t1*t1 + t2*t2;
        W4[k] = p0*t0 + p1*t1 + p2*t2;
    }
#pragma unroll
    for (int j = 0; j < DPT; ++j) {
        P[0][j] = W0[j] + W0[j+1] + W0[j+2];
        P[1][j] = W1[j] + W1[j+1] + W1[j+2];
        P[2][j] = W2[j] + W2[j+1] + W2[j+2];
        P[3][j] = W3[j] + W3[j+1] + W3[j+2];
        P[4][j] = W4[j] + W4[j+1] + W4[j+2];
    }
}

__device__ __forceinline__ float ncc_row3(const float (&Pm)[5][DPT],
                                          const float (&Pc)[5][DPT],
                                          const float (&Pn)[5][DPT])
{
    const float inv = 1.0f / 27.0f;
    float acc = 0.f;
#pragma unroll
    for (int j = 0; j < DPT; ++j) {
        const float sI  = Pm[0][j] + Pc[0][j] + Pn[0][j];
        const float sJ  = Pm[1][j] + Pc[1][j] + Pn[1][j];
        const float sII = Pm[2][j] + Pc[2][j] + Pn[2][j];
        const float sJJ = Pm[3][j] + Pc[3][j] + Pn[3][j];
        const float sIJ = Pm[4][j] + Pc[4][j] + Pn[4][j];
        const float uI = sI * inv;
        const float uJ = sJ * inv;
        const float cross = sIJ - uI * sJ;
        const float pvar  = sII - uI * sI;
        const float tvar  = sJJ - uJ * sJ;
        acc += (cross * cross) * __builtin_amdgcn_rcpf(tvar * pvar + 1e-5f);
    }
    return acc;
}

__device__ __forceinline__ void rot2(float (&Pm)[5][DPT], float (&Pc)[5][DPT],
                                     const float (&Pn)[5][DPT])
{
#pragma unroll
    for (int c = 0; c < 5; ++c)
#pragma unroll
        for (int j = 0; j < DPT; ++j) { Pm[c][j] = Pc[c][j]; Pc[c][j] = Pn[c][j]; }
}

__global__ __launch_bounds__(256, 2)
void FusedLocalNormalizedCrossCorrelationLoss_37838661877790_kernel(
    const float* __restrict__ pred, const float* __restrict__ targ,
    double* __restrict__ acc_out)
{
    const int tx = threadIdx.x;                 // 16 d-quads
    const int ty = threadIdx.y;                 // 16 w rows
    const int d0 = (blockIdx.x * TX + tx) * DPT;
    const int w  = blockIdx.y * TY + ty;
    const int bz = blockIdx.z;
    const int b  = bz >> 5;                     // 2 batches
    const int h0 = (bz & 31) * HCHUNK;          // 32 h-chunks

    Raw rA, rB;
    float Pm[5][DPT], Pc[5][DPT], Pn[5][DPT];

    // Prologue: planes h0-1, h0 consumed immediately; h0+1, h0+2 in flight.
    load_raw(pred, targ, b, h0 - 1, w, d0, rA);
    load_raw(pred, targ, b, h0,     w, d0, rB);
    plane_sums(rA, Pm);
    load_raw(pred, targ, b, h0 + 1, w, d0, rA);
    plane_sums(rB, Pc);
    load_raw(pred, targ, b, h0 + 2, w, d0, rB);

    float acc = 0.f;

    // Manually unrolled pipeline: iter i consumes plane h0+1+i, prefetches
    // plane h0+3+i into the just-consumed buffer (2-iteration distance).
    plane_sums(rA, Pn);                                   // i=0: plane h0+1
    load_raw(pred, targ, b, h0 + 3, w, d0, rA);
    acc += ncc_row3(Pm, Pc, Pn); rot2(Pm, Pc, Pn);

    plane_sums(rB, Pn);                                   // i=1: plane h0+2
    load_raw(pred, targ, b, h0 + 4, w, d0, rB);
    acc += ncc_row3(Pm, Pc, Pn); rot2(Pm, Pc, Pn);

    plane_sums(rA, Pn);                                   // i=2: plane h0+3
    load_raw(pred, targ, b, h0 + 5, w, d0, rA);
    acc += ncc_row3(Pm, Pc, Pn); rot2(Pm, Pc, Pn);

    plane_sums(rB, Pn);                                   // i=3: plane h0+4
    load_raw(pred, targ, b, h0 + 6, w, d0, rB);
    acc += ncc_row3(Pm, Pc, Pn); rot2(Pm, Pc, Pn);

    plane_sums(rA, Pn);                                   // i=4: plane h0+5
    acc += ncc_row3(Pm, Pc, Pn); rot2(Pm, Pc, Pn);

    plane_sums(rB, Pn);                                   // i=5: plane h0+6
    acc += ncc_row3(Pm, Pc, Pn);

    // Reduction: wave shuffle tree -> LDS -> one fp64 atomic per block.
#pragma unroll
    for (int off = 32; off > 0; off >>= 1)
        acc += __shfl_down(acc, off, 64);
    __shared__ float wacc[4];
    const int tid = ty * TX + tx;
    if ((tid & 63) == 0) wacc[tid >> 6] = acc;
    __syncthreads();
    if (tid == 0) {
        const double s = (double)wacc[0] + (double)wacc[1]
                       + (double)wacc[2] + (double)wacc[3];
        atomicAdd(acc_out, s);
    }
}

__global__ void ncc_finalize(const double* __restrict__ acc,
                             float* __restrict__ out)
{
    const double n = (double)((size_t)DIMB * DIMS * DIMS * DIMS);
    out[0] = (float)(-acc[0] / n);
}

extern "C" void kernel_launch(void* const* d_in, const int* in_sizes, int n_in,
                              void* d_out, int out_size, void* d_ws, size_t ws_size,
                              hipStream_t stream) {
    const float* pred = (const float*)d_in[0];
    const float* targ = (const float*)d_in[1];
    double* acc = (double*)d_ws;

    hipMemsetAsync(d_ws, 0, sizeof(double), stream);

    dim3 block(TX, TY, 1);
    dim3 grid(DIMS / (TX * DPT), DIMS / TY, DIMB * (DIMS / HCHUNK)); // 3 x 12 x 64
    FusedLocalNormalizedCrossCorrelationLoss_37838661877790_kernel
        <<<grid, block, 0, stream>>>(pred, targ, acc);
    ncc_finalize<<<1, 1, 0, stream>>>(acc, (float*)d_out);
}